// Round 1
// baseline (690.597 us; speedup 1.0000x reference)
//
#include <hip/hip_runtime.h>

// Dequant: groups of 32 4-bit values packed as 17 int32 words/group
// (16 data words, low byte = two nibbles; word 16 = biased log2 scale).
// out[g*32 + 2b]   = (low_nibble(word b)  - clamp_max) / max_val * 2^(s-127)
// out[g*32 + 2b+1] = (high_nibble(word b) - clamp_max) / max_val * 2^(s-127)
//
// One thread per float4 of output: tid -> g = tid>>3, j0 = (tid&7)*4.
// Output float offset = g*32 + j0 = tid*4  -> perfectly coalesced dwordx4 stores.

constexpr int kGroupSize = 32;
constexpr int kPGS = kGroupSize / 2 + 1;  // 17 words per packed group

__global__ __launch_bounds__(256) void dequant_mxfp4_kernel(
    const int* __restrict__ packed,
    const int* __restrict__ ebits_p,
    const int* __restrict__ mbits_p,
    float* __restrict__ out,
    int n_vec4)
{
    int tid = blockIdx.x * 256 + threadIdx.x;
    if (tid >= n_vec4) return;

    // Uniform scalar params (s_load; effectively free, memory-bound kernel).
    int ebits = ebits_p[0];
    int mbits = mbits_p[0];
    float clamp_max = (float)(1 << ((1 << ebits) - 1));          // 8 for ebits=2
    float inv_max   = 1.0f / (clamp_max * (2.0f - exp2f((float)(-mbits))));  // 1/12

    int g  = tid >> 3;          // group index (8 threads per group)
    int b0 = (tid & 7) * 2;     // first data word this thread handles
    int base = g * kPGS;

    int w0 = packed[base + b0];
    int w1 = packed[base + b0 + 1];
    int s  = packed[base + kGroupSize / 2];  // scale word (8-lane broadcast)

    int e = s - 127;
    e = min(max(e, -126), 127);
    float coef = ldexpf(1.0f, e) * inv_max;  // 2^e / max_val

    float4 r;
    r.x = ((float)(w0 & 15)        - clamp_max) * coef;
    r.y = ((float)((w0 >> 4) & 15) - clamp_max) * coef;
    r.z = ((float)(w1 & 15)        - clamp_max) * coef;
    r.w = ((float)((w1 >> 4) & 15) - clamp_max) * coef;

    reinterpret_cast<float4*>(out)[tid] = r;
}

extern "C" void kernel_launch(void* const* d_in, const int* in_sizes, int n_in,
                              void* d_out, int out_size, void* d_ws, size_t ws_size,
                              hipStream_t stream) {
    const int* packed  = (const int*)d_in[0];
    // d_in[1] = group_size (structural, =32; packing geometry hardcoded)
    const int* ebits_p = (const int*)d_in[2];
    const int* mbits_p = (const int*)d_in[3];
    float* out = (float*)d_out;

    int n_vec4 = out_size / 4;                 // 33,554,432 float4s
    int grid = (n_vec4 + 255) / 256;           // 131,072 blocks
    dequant_mxfp4_kernel<<<grid, 256, 0, stream>>>(packed, ebits_p, mbits_p, out, n_vec4);
}